// Round 7
// baseline (417.534 us; speedup 1.0000x reference)
//
#include <hip/hip_runtime.h>

#define D 128
#define SCAN_ELEMS 4096   // elements per scan block (256 threads x 16)

typedef __attribute__((ext_vector_type(8))) short short8;
typedef __attribute__((ext_vector_type(4))) float f32x4;

// ---------------- precompute kernels ----------------
// deg[] counts REAL edges only (self-loop handled as +1 at use sites).

__global__ void count_kernel(const int* __restrict__ dst, int* __restrict__ deg,
                             int* __restrict__ rank, int e) {
    int i = blockIdx.x * blockDim.x + threadIdx.x;
    if (i < e) rank[i] = atomicAdd(&deg[dst[i]], 1);
}

__global__ __launch_bounds__(256) void scanA_kernel(const int* __restrict__ deg,
                                                    int* __restrict__ blkSums, int n) {
    __shared__ int waveSums[4];
    int t = threadIdx.x;
    int base = blockIdx.x * SCAN_ELEMS + t * 16;
    int s = 0;
    if (base + 16 <= n) {
        const int4* p = reinterpret_cast<const int4*>(deg + base);
        #pragma unroll
        for (int k = 0; k < 4; ++k) {
            int4 v = p[k];
            s += v.x + v.y + v.z + v.w;
        }
    } else {
        for (int k = 0; k < 16; ++k) {
            int i = base + k;
            if (i < n) s += deg[i];
        }
    }
    #pragma unroll
    for (int off = 32; off > 0; off >>= 1) s += __shfl_down(s, off);
    int lane = t & 63, w = t >> 6;
    if (lane == 0) waveSums[w] = s;
    __syncthreads();
    if (t == 0) blkSums[blockIdx.x] = waveSums[0] + waveSums[1] + waveSums[2] + waveSums[3];
}

// scanC: block prefix from blkSums (reduction over preceding blocks, folded in)
__global__ __launch_bounds__(256) void scanC_kernel(const int* __restrict__ deg,
                                                    const int* __restrict__ blkSums,
                                                    int* __restrict__ offsets,
                                                    float* __restrict__ dinv, int n, int nblk) {
    __shared__ int waveSums[4];
    __shared__ int blkBase;
    int t = threadIdx.x;
    int lane = t & 63, w = t >> 6;

    if (t < 64) {   // first wave: sum of blkSums[0..blockIdx.x-1]
        int s = (t < nblk && t < blockIdx.x) ? blkSums[t] : 0;
        #pragma unroll
        for (int off = 32; off > 0; off >>= 1) s += __shfl_down(s, off);
        if (t == 0) blkBase = s;
    }

    int base = blockIdx.x * SCAN_ELEMS + t * 16;
    int v[16];
    int s = 0;
    #pragma unroll
    for (int k = 0; k < 16; ++k) {
        int i = base + k;
        int d = (i < n) ? deg[i] : 0;
        v[k] = d;
        s += d;
    }
    int incl = s;
    #pragma unroll
    for (int off = 1; off < 64; off <<= 1) {
        int u = __shfl_up(incl, off);
        if (lane >= off) incl += u;
    }
    if (lane == 63) waveSums[w] = incl;
    __syncthreads();
    int waveOff = 0;
    for (int i = 0; i < 4; ++i) if (i < w) waveOff += waveSums[i];
    int off0 = blkBase + waveOff + incl - s;

    #pragma unroll
    for (int k = 0; k < 16; ++k) {
        int i = base + k;
        if (i < n) {
            offsets[i] = off0;
            dinv[i] = rsqrtf((float)(v[k] + 1));   // +1 self-loop
            off0 += v[k];
        }
    }
}

__global__ void fill_kernel(const int* __restrict__ src, const int* __restrict__ dst,
                            const int* __restrict__ offsets, const int* __restrict__ rank,
                            int* __restrict__ csr_src, int e) {
    int i = blockIdx.x * blockDim.x + threadIdx.x;
    if (i < e) {
        csr_src[offsets[dst[i]] + rank[i]] = src[i];
    }
}

// ---------------- split-bf16 MFMA GEMM: out[r][c] = dinv[r]*(A[r][:] @ W[:][c]) ----------------
// x = hi + lo (bf16 pieces); x@w ~= hi@hi + hi@lo + lo@hi  (fp32 accum, ~1e-5 rel err)
// Block: 256 thr / 4 waves, 64 rows x 128 cols. Wave w: rows w*16..+15, 8 col-tiles.
// A-frags straight from global (rows block-exclusive); W swizzled in LDS per k-half.

__device__ inline void f2bf(float f, short& hi, short& lo) {
    union { float f; unsigned u; } a; a.f = f;
    unsigned r = a.u + 0x7fffu + ((a.u >> 16) & 1u);       // RNE to bf16
    hi = (short)(r >> 16);
    union { unsigned u; float f; } h; h.u = ((unsigned)(unsigned short)hi) << 16;
    union { float f; unsigned u; } b; b.f = f - h.f;
    unsigned r2 = b.u + 0x7fffu + ((b.u >> 16) & 1u);
    lo = (short)(r2 >> 16);
}

__global__ __launch_bounds__(256, 4) void gemm_kernel(const float* __restrict__ A,
                                                      const float* __restrict__ Wg,
                                                      const float* __restrict__ dinv,
                                                      float* __restrict__ outp, int n) {
    __shared__ short Bhi[2][8][64][8];   // [kt][ct][lane][j]  (one k-half: 64 k-rows)
    __shared__ short Blo[2][8][64][8];

    int t = threadIdx.x;
    int w = t >> 6;
    int lane = t & 63;
    int quad = lane >> 4;
    int m = lane & 15;

    int rowBase = blockIdx.x * 64 + w * 16;
    int arow = rowBase + m;

    f32x4 acc[8];
    #pragma unroll
    for (int ct = 0; ct < 8; ++ct) acc[ct] = (f32x4){0.f, 0.f, 0.f, 0.f};

    for (int kh = 0; kh < 2; ++kh) {
        __syncthreads();
        // stage W rows [kh*64, kh*64+64) swizzled to fragment order
        for (int idx = t; idx < 64 * 32; idx += 256) {
            int krel = idx >> 5;            // 0..63
            int c4   = (idx & 31) << 2;     // 0..124
            float4 v = *reinterpret_cast<const float4*>(Wg + (size_t)(kh * 64 + krel) * D + c4);
            int kt = krel >> 5, kk = krel & 31, q = kk >> 3, j = kk & 7;
            float vv[4] = {v.x, v.y, v.z, v.w};
            #pragma unroll
            for (int u = 0; u < 4; ++u) {
                int c = c4 + u;
                int ct = c >> 4, mm = c & 15, ln = q * 16 + mm;
                short hi, lo; f2bf(vv[u], hi, lo);
                Bhi[kt][ct][ln][j] = hi;
                Blo[kt][ct][ln][j] = lo;
            }
        }
        __syncthreads();

        #pragma unroll
        for (int kt = 0; kt < 2; ++kt) {
            short8 a_hi, a_lo;
            if (arow < n) {
                const float* ap = A + (size_t)arow * D + kh * 64 + kt * 32 + quad * 8;
                float4 f0 = *reinterpret_cast<const float4*>(ap);
                float4 f1 = *reinterpret_cast<const float4*>(ap + 4);
                float fv[8] = {f0.x, f0.y, f0.z, f0.w, f1.x, f1.y, f1.z, f1.w};
                #pragma unroll
                for (int j = 0; j < 8; ++j) { short h, l; f2bf(fv[j], h, l); a_hi[j] = h; a_lo[j] = l; }
            } else {
                #pragma unroll
                for (int j = 0; j < 8; ++j) { a_hi[j] = 0; a_lo[j] = 0; }
            }
            #pragma unroll
            for (int ct = 0; ct < 8; ++ct) {
                short8 b_hi = *reinterpret_cast<short8*>(&Bhi[kt][ct][lane][0]);
                short8 b_lo = *reinterpret_cast<short8*>(&Blo[kt][ct][lane][0]);
                acc[ct] = __builtin_amdgcn_mfma_f32_16x16x32_bf16(a_hi, b_hi, acc[ct], 0, 0, 0);
                acc[ct] = __builtin_amdgcn_mfma_f32_16x16x32_bf16(a_hi, b_lo, acc[ct], 0, 0, 0);
                acc[ct] = __builtin_amdgcn_mfma_f32_16x16x32_bf16(a_lo, b_hi, acc[ct], 0, 0, 0);
            }
        }
    }

    // epilogue: C/D layout col=lane&15, row=quad*4+reg  [verified mapping]
    #pragma unroll
    for (int r = 0; r < 4; ++r) {
        int orow = rowBase + quad * 4 + r;
        if (orow < n) {
            float s = dinv[orow];
            float* o = outp + (size_t)orow * D + m;
            #pragma unroll
            for (int ct = 0; ct < 8; ++ct) o[ct * 16] = acc[ct][r] * s;
        }
    }
}

// ---------------- aggregation (+ optional fused fc head), fp32 ----------------
// xws rows pre-scaled by dinv[row]:
//   h[d] = relu( dinv[d] * (sum_{e:s->d} xws[s] + xws[d]) + b )
__global__ __launch_bounds__(256) void agg_kernel(const float* __restrict__ xws,
                                                  const int* __restrict__ csr_src,
                                                  const int* __restrict__ offsets,
                                                  const int* __restrict__ deg,
                                                  const float* __restrict__ dinv,
                                                  const float* __restrict__ bias,
                                                  float* __restrict__ outp,
                                                  const float* __restrict__ fcw,
                                                  const float* __restrict__ fcb,
                                                  float* __restrict__ fcout,
                                                  int n) {
    int wave = (blockIdx.x * blockDim.x + threadIdx.x) >> 6;
    int lane = threadIdx.x & 63;
    if (wave >= n) return;
    int node = wave;
    int half = lane >> 5;
    int l32  = lane & 31;
    size_t col = (size_t)(l32 << 2);

    int base = offsets[node];
    int cnt  = deg[node];

    float di = dinv[node];
    float4 vs = *reinterpret_cast<const float4*>(xws + (size_t)node * D + col);
    float4 b  = *reinterpret_cast<const float4*>(bias + col);

    float4 acc0 = make_float4(0.f, 0.f, 0.f, 0.f);
    float4 acc1 = make_float4(0.f, 0.f, 0.f, 0.f);
    float4 acc2 = make_float4(0.f, 0.f, 0.f, 0.f);
    float4 acc3 = make_float4(0.f, 0.f, 0.f, 0.f);

    if (cnt <= 64) {
        int idx = (lane < cnt) ? csr_src[base + lane] : 0;
        int j = 0;
        for (; j + 8 <= cnt; j += 8) {
            int s0 = __shfl(idx, j     + half);
            int s1 = __shfl(idx, j + 2 + half);
            int s2 = __shfl(idx, j + 4 + half);
            int s3 = __shfl(idx, j + 6 + half);
            float4 v0 = *reinterpret_cast<const float4*>(xws + (size_t)s0 * D + col);
            float4 v1 = *reinterpret_cast<const float4*>(xws + (size_t)s1 * D + col);
            float4 v2 = *reinterpret_cast<const float4*>(xws + (size_t)s2 * D + col);
            float4 v3 = *reinterpret_cast<const float4*>(xws + (size_t)s3 * D + col);
            acc0.x += v0.x; acc0.y += v0.y; acc0.z += v0.z; acc0.w += v0.w;
            acc1.x += v1.x; acc1.y += v1.y; acc1.z += v1.z; acc1.w += v1.w;
            acc2.x += v2.x; acc2.y += v2.y; acc2.z += v2.z; acc2.w += v2.w;
            acc3.x += v3.x; acc3.y += v3.y; acc3.z += v3.z; acc3.w += v3.w;
        }
        for (; j + 2 <= cnt; j += 2) {
            int s0 = __shfl(idx, j + half);
            float4 v0 = *reinterpret_cast<const float4*>(xws + (size_t)s0 * D + col);
            acc0.x += v0.x; acc0.y += v0.y; acc0.z += v0.z; acc0.w += v0.w;
        }
        if (j < cnt) {
            int s0 = __shfl(idx, j);
            if (half == 0) {
                float4 v0 = *reinterpret_cast<const float4*>(xws + (size_t)s0 * D + col);
                acc1.x += v0.x; acc1.y += v0.y; acc1.z += v0.z; acc1.w += v0.w;
            }
        }
    } else {
        int j = 0;
        for (; j + 2 <= cnt; j += 2) {
            int s = csr_src[base + j + half];
            float4 v = *reinterpret_cast<const float4*>(xws + (size_t)s * D + col);
            acc0.x += v.x; acc0.y += v.y; acc0.z += v.z; acc0.w += v.w;
        }
        if (j < cnt && half == 0) {
            int s = csr_src[base + j];
            float4 v = *reinterpret_cast<const float4*>(xws + (size_t)s * D + col);
            acc1.x += v.x; acc1.y += v.y; acc1.z += v.z; acc1.w += v.w;
        }
    }

    acc0.x += acc1.x + acc2.x + acc3.x;
    acc0.y += acc1.y + acc2.y + acc3.y;
    acc0.z += acc1.z + acc2.z + acc3.z;
    acc0.w += acc1.w + acc2.w + acc3.w;
    acc0.x += __shfl_down(acc0.x, 32);
    acc0.y += __shfl_down(acc0.y, 32);
    acc0.z += __shfl_down(acc0.z, 32);
    acc0.w += __shfl_down(acc0.w, 32);

    float4 r;
    r.x = fmaxf(di * (acc0.x + vs.x) + b.x, 0.f);
    r.y = fmaxf(di * (acc0.y + vs.y) + b.y, 0.f);
    r.z = fmaxf(di * (acc0.z + vs.z) + b.z, 0.f);
    r.w = fmaxf(di * (acc0.w + vs.w) + b.w, 0.f);

    if (fcw == nullptr) {
        if (half == 0)
            *reinterpret_cast<float4*>(outp + (size_t)node * D + col) = r;
    } else {
        float4 wv = *reinterpret_cast<const float4*>(fcw + col);
        float s = (half == 0) ? (r.x * wv.x + r.y * wv.y + r.z * wv.z + r.w * wv.w) : 0.f;
        #pragma unroll
        for (int off = 32; off > 0; off >>= 1) s += __shfl_down(s, off);
        if (lane == 0) fcout[node] = s + fcb[0];
    }
}

// ---------------- launch ----------------

extern "C" void kernel_launch(void* const* d_in, const int* in_sizes, int n_in,
                              void* d_out, int out_size, void* d_ws, size_t ws_size,
                              hipStream_t stream) {
    const float* x   = (const float*)d_in[0];
    const int*   ei  = (const int*)d_in[1];
    const float* W1  = (const float*)d_in[2];
    const float* b1  = (const float*)d_in[3];
    const float* W2  = (const float*)d_in[4];
    const float* b2  = (const float*)d_in[5];
    const float* W3  = (const float*)d_in[6];
    const float* b3  = (const float*)d_in[7];
    const float* Wfc = (const float*)d_in[8];
    const float* bfc = (const float*)d_in[9];
    float* outp = (float*)d_out;

    const int n = in_sizes[0] / D;        // 50000
    const int e = in_sizes[1] / 2;        // 800000
    const int* src = ei;
    const int* dst = ei + e;

    char* ws = (char*)d_ws;
    size_t off = 0;
    auto alloc = [&](size_t bytes) {
        void* p = ws + off;
        off += (bytes + 255) & ~(size_t)255;
        return p;
    };
    int*   deg     = (int*)alloc((size_t)n * 4);
    size_t zero_bytes = off;              // deg zeroed
    int*   offsets = (int*)alloc((size_t)n * 4);
    float* dinv    = (float*)alloc((size_t)n * 4);
    int*   blkSums = (int*)alloc(64 * 4);
    int*   rank    = (int*)alloc((size_t)e * 4);
    int*   csr_src = (int*)alloc((size_t)e * 4);
    float* buf0    = (float*)alloc((size_t)n * D * 4);
    float* buf1    = (float*)alloc((size_t)n * D * 4);

    int eb256 = (e + 255) / 256;
    int scan_blocks = (n + SCAN_ELEMS - 1) / SCAN_ELEMS;   // 13 (<=64)

    hipMemsetAsync(ws, 0, zero_bytes, stream);
    count_kernel<<<eb256, 256, 0, stream>>>(dst, deg, rank, e);
    scanA_kernel<<<scan_blocks, 256, 0, stream>>>(deg, blkSums, n);
    scanC_kernel<<<scan_blocks, 256, 0, stream>>>(deg, blkSums, offsets, dinv, n, scan_blocks);
    fill_kernel <<<eb256, 256, 0, stream>>>(src, dst, offsets, rank, csr_src, e);

    int gemm_blocks = (n + 63) / 64;      // 782
    int agg_blocks  = (n + 3) / 4;

    gemm_kernel<<<gemm_blocks, 256, 0, stream>>>(x, W1, dinv, buf0, n);
    agg_kernel <<<agg_blocks, 256, 0, stream>>>(buf0, csr_src, offsets, deg, dinv, b1, buf1,
                                                nullptr, nullptr, nullptr, n);
    gemm_kernel<<<gemm_blocks, 256, 0, stream>>>(buf1, W2, dinv, buf0, n);
    agg_kernel <<<agg_blocks, 256, 0, stream>>>(buf0, csr_src, offsets, deg, dinv, b2, buf1,
                                                nullptr, nullptr, nullptr, n);
    gemm_kernel<<<gemm_blocks, 256, 0, stream>>>(buf1, W3, dinv, buf0, n);
    agg_kernel <<<agg_blocks, 256, 0, stream>>>(buf0, csr_src, offsets, deg, dinv, b3, nullptr,
                                                Wfc, bfc, outp, n);
}

// Round 8
// 364.310 us; speedup vs baseline: 1.1461x; 1.1461x over previous
//
#include <hip/hip_runtime.h>

#define D 128
#define SCAN_ELEMS 4096   // elements per scan block (256 threads x 16)

typedef __attribute__((ext_vector_type(8))) short short8;
typedef __attribute__((ext_vector_type(4))) float f32x4;

// ---------------- precompute kernels ----------------
// deg[] counts REAL edges only (self-loop handled as +1 at use sites).

__global__ void count_kernel(const int* __restrict__ dst, int* __restrict__ deg,
                             int* __restrict__ rank, int e) {
    int i = blockIdx.x * blockDim.x + threadIdx.x;
    if (i < e) rank[i] = atomicAdd(&deg[dst[i]], 1);
}

__global__ __launch_bounds__(256) void scanA_kernel(const int* __restrict__ deg,
                                                    int* __restrict__ blkSums, int n) {
    __shared__ int waveSums[4];
    int t = threadIdx.x;
    int base = blockIdx.x * SCAN_ELEMS + t * 16;
    int s = 0;
    if (base + 16 <= n) {
        const int4* p = reinterpret_cast<const int4*>(deg + base);
        #pragma unroll
        for (int k = 0; k < 4; ++k) {
            int4 v = p[k];
            s += v.x + v.y + v.z + v.w;
        }
    } else {
        for (int k = 0; k < 16; ++k) {
            int i = base + k;
            if (i < n) s += deg[i];
        }
    }
    #pragma unroll
    for (int off = 32; off > 0; off >>= 1) s += __shfl_down(s, off);
    int lane = t & 63, w = t >> 6;
    if (lane == 0) waveSums[w] = s;
    __syncthreads();
    if (t == 0) blkSums[blockIdx.x] = waveSums[0] + waveSums[1] + waveSums[2] + waveSums[3];
}

// scanC: block prefix from blkSums (reduction over preceding blocks, folded in)
__global__ __launch_bounds__(256) void scanC_kernel(const int* __restrict__ deg,
                                                    const int* __restrict__ blkSums,
                                                    int* __restrict__ offsets,
                                                    float* __restrict__ dinv, int n, int nblk) {
    __shared__ int waveSums[4];
    __shared__ int blkBase;
    int t = threadIdx.x;
    int lane = t & 63, w = t >> 6;

    if (t < 64) {   // first wave: sum of blkSums[0..blockIdx.x-1]
        int s = (t < nblk && t < blockIdx.x) ? blkSums[t] : 0;
        #pragma unroll
        for (int off = 32; off > 0; off >>= 1) s += __shfl_down(s, off);
        if (t == 0) blkBase = s;
    }

    int base = blockIdx.x * SCAN_ELEMS + t * 16;
    int v[16];
    int s = 0;
    #pragma unroll
    for (int k = 0; k < 16; ++k) {
        int i = base + k;
        int d = (i < n) ? deg[i] : 0;
        v[k] = d;
        s += d;
    }
    int incl = s;
    #pragma unroll
    for (int off = 1; off < 64; off <<= 1) {
        int u = __shfl_up(incl, off);
        if (lane >= off) incl += u;
    }
    if (lane == 63) waveSums[w] = incl;
    __syncthreads();
    int waveOff = 0;
    for (int i = 0; i < 4; ++i) if (i < w) waveOff += waveSums[i];
    int off0 = blkBase + waveOff + incl - s;

    #pragma unroll
    for (int k = 0; k < 16; ++k) {
        int i = base + k;
        if (i < n) {
            offsets[i] = off0;
            dinv[i] = rsqrtf((float)(v[k] + 1));   // +1 self-loop
            off0 += v[k];
        }
    }
}

__global__ void fill_kernel(const int* __restrict__ src, const int* __restrict__ dst,
                            const int* __restrict__ offsets, const int* __restrict__ rank,
                            int* __restrict__ csr_src, int e) {
    int i = blockIdx.x * blockDim.x + threadIdx.x;
    if (i < e) {
        csr_src[offsets[dst[i]] + rank[i]] = src[i];
    }
}

// ---------------- split-bf16 helpers ----------------
__device__ inline void f2bf(float f, short& hi, short& lo) {
    union { float f; unsigned u; } a; a.f = f;
    unsigned r = a.u + 0x7fffu + ((a.u >> 16) & 1u);       // RNE to bf16
    hi = (short)(r >> 16);
    union { unsigned u; float f; } h; h.u = ((unsigned)(unsigned short)hi) << 16;
    union { float f; unsigned u; } b; b.f = f - h.f;
    unsigned r2 = b.u + 0x7fffu + ((b.u >> 16) & 1u);
    lo = (short)(r2 >> 16);
}

// Pre-split + swizzle the three 128x128 weight matrices into MFMA B-fragment
// order. Per layer: hi[16384 shorts] then lo[16384 shorts] (64KB total).
// Fragment index: Bsw[layer*32768 + ((ktile*8+ct)*64 + lane)*8 + j] where
// lane = quad*16 + (col&15), k = ktile*32 + quad*8 + j.
__global__ __launch_bounds__(256) void wsplit_kernel(const float* __restrict__ W1,
                                                     const float* __restrict__ W2,
                                                     const float* __restrict__ W3,
                                                     short* __restrict__ Bsw) {
    int tid = blockIdx.x * 256 + threadIdx.x;   // 0 .. 3*16384-1
    int layer = tid >> 14;
    int rem = tid & 16383;
    int k = rem >> 7, c = rem & 127;
    const float* Wg = (layer == 0) ? W1 : ((layer == 1) ? W2 : W3);
    float v = Wg[k * 128 + c];
    short hi, lo; f2bf(v, hi, lo);
    int ktile = k >> 5, kk = k & 31, q = kk >> 3, j = kk & 7;
    int ct = c >> 4, mm = c & 15, lane = q * 16 + mm;
    int idx = layer * 32768 + ((ktile * 8 + ct) * 64 + lane) * 8 + j;
    Bsw[idx] = hi;
    Bsw[idx + 16384] = lo;
}

// ---------------- split-bf16 MFMA GEMM: out[r][c] = dinv[r]*(A[r][:] @ W[:][c]) ----------------
// x@w ~= hi@hi + hi@lo + lo@hi (fp32 accum, ~1e-5 rel err).
// No LDS, no barriers: B-frags read directly from pre-swizzled global array
// (same 64KB for every block -> L1/L2 broadcast); A converted on the fly.
__global__ __launch_bounds__(256) void gemm_kernel(const float* __restrict__ A,
                                                   const short* __restrict__ Bsw,
                                                   const float* __restrict__ dinv,
                                                   float* __restrict__ outp, int n) {
    int t = threadIdx.x;
    int w = t >> 6;
    int lane = t & 63;
    int quad = lane >> 4;
    int m = lane & 15;

    int rowBase = blockIdx.x * 64 + w * 16;
    int arow = rowBase + m;
    bool valid = arow < n;
    const float* ap = A + (size_t)(valid ? arow : 0) * D + quad * 8;

    f32x4 acc[8];
    #pragma unroll
    for (int ct = 0; ct < 8; ++ct) acc[ct] = (f32x4){0.f, 0.f, 0.f, 0.f};

    #pragma unroll
    for (int kt = 0; kt < 4; ++kt) {
        short8 a_hi, a_lo;
        {
            float4 f0 = *reinterpret_cast<const float4*>(ap + kt * 32);
            float4 f1 = *reinterpret_cast<const float4*>(ap + kt * 32 + 4);
            float fv[8] = {f0.x, f0.y, f0.z, f0.w, f1.x, f1.y, f1.z, f1.w};
            #pragma unroll
            for (int j = 0; j < 8; ++j) {
                short h, l; f2bf(valid ? fv[j] : 0.f, h, l);
                a_hi[j] = h; a_lo[j] = l;
            }
        }
        const short* bp = Bsw + (kt * 8 * 64 + lane) * 8;
        #pragma unroll
        for (int ct = 0; ct < 8; ++ct) {
            short8 b_hi = *reinterpret_cast<const short8*>(bp + ct * 512);
            short8 b_lo = *reinterpret_cast<const short8*>(bp + 16384 + ct * 512);
            acc[ct] = __builtin_amdgcn_mfma_f32_16x16x32_bf16(a_hi, b_hi, acc[ct], 0, 0, 0);
            acc[ct] = __builtin_amdgcn_mfma_f32_16x16x32_bf16(a_hi, b_lo, acc[ct], 0, 0, 0);
            acc[ct] = __builtin_amdgcn_mfma_f32_16x16x32_bf16(a_lo, b_hi, acc[ct], 0, 0, 0);
        }
    }

    // epilogue: C/D layout col=lane&15, row=quad*4+reg
    #pragma unroll
    for (int r = 0; r < 4; ++r) {
        int orow = rowBase + quad * 4 + r;
        if (orow < n) {
            float s = dinv[orow];
            float* o = outp + (size_t)orow * D + m;
            #pragma unroll
            for (int ct = 0; ct < 8; ++ct) o[ct * 16] = acc[ct][r] * s;
        }
    }
}

// ---------------- aggregation (+ optional fused fc head), fp32 ----------------
// xws rows pre-scaled by dinv[row]:
//   h[d] = relu( dinv[d] * (sum_{e:s->d} xws[s] + xws[d]) + b )
__global__ __launch_bounds__(256) void agg_kernel(const float* __restrict__ xws,
                                                  const int* __restrict__ csr_src,
                                                  const int* __restrict__ offsets,
                                                  const int* __restrict__ deg,
                                                  const float* __restrict__ dinv,
                                                  const float* __restrict__ bias,
                                                  float* __restrict__ outp,
                                                  const float* __restrict__ fcw,
                                                  const float* __restrict__ fcb,
                                                  float* __restrict__ fcout,
                                                  int n) {
    int wave = (blockIdx.x * blockDim.x + threadIdx.x) >> 6;
    int lane = threadIdx.x & 63;
    if (wave >= n) return;
    int node = wave;
    int half = lane >> 5;
    int l32  = lane & 31;
    size_t col = (size_t)(l32 << 2);

    int base = offsets[node];
    int cnt  = deg[node];

    float di = dinv[node];
    float4 vs = *reinterpret_cast<const float4*>(xws + (size_t)node * D + col);
    float4 b  = *reinterpret_cast<const float4*>(bias + col);

    float4 acc0 = make_float4(0.f, 0.f, 0.f, 0.f);
    float4 acc1 = make_float4(0.f, 0.f, 0.f, 0.f);
    float4 acc2 = make_float4(0.f, 0.f, 0.f, 0.f);
    float4 acc3 = make_float4(0.f, 0.f, 0.f, 0.f);

    if (cnt <= 64) {
        int idx = (lane < cnt) ? csr_src[base + lane] : 0;
        int j = 0;
        for (; j + 8 <= cnt; j += 8) {
            int s0 = __shfl(idx, j     + half);
            int s1 = __shfl(idx, j + 2 + half);
            int s2 = __shfl(idx, j + 4 + half);
            int s3 = __shfl(idx, j + 6 + half);
            float4 v0 = *reinterpret_cast<const float4*>(xws + (size_t)s0 * D + col);
            float4 v1 = *reinterpret_cast<const float4*>(xws + (size_t)s1 * D + col);
            float4 v2 = *reinterpret_cast<const float4*>(xws + (size_t)s2 * D + col);
            float4 v3 = *reinterpret_cast<const float4*>(xws + (size_t)s3 * D + col);
            acc0.x += v0.x; acc0.y += v0.y; acc0.z += v0.z; acc0.w += v0.w;
            acc1.x += v1.x; acc1.y += v1.y; acc1.z += v1.z; acc1.w += v1.w;
            acc2.x += v2.x; acc2.y += v2.y; acc2.z += v2.z; acc2.w += v2.w;
            acc3.x += v3.x; acc3.y += v3.y; acc3.z += v3.z; acc3.w += v3.w;
        }
        for (; j + 2 <= cnt; j += 2) {
            int s0 = __shfl(idx, j + half);
            float4 v0 = *reinterpret_cast<const float4*>(xws + (size_t)s0 * D + col);
            acc0.x += v0.x; acc0.y += v0.y; acc0.z += v0.z; acc0.w += v0.w;
        }
        if (j < cnt) {
            int s0 = __shfl(idx, j);
            if (half == 0) {
                float4 v0 = *reinterpret_cast<const float4*>(xws + (size_t)s0 * D + col);
                acc1.x += v0.x; acc1.y += v0.y; acc1.z += v0.z; acc1.w += v0.w;
            }
        }
    } else {
        int j = 0;
        for (; j + 2 <= cnt; j += 2) {
            int s = csr_src[base + j + half];
            float4 v = *reinterpret_cast<const float4*>(xws + (size_t)s * D + col);
            acc0.x += v.x; acc0.y += v.y; acc0.z += v.z; acc0.w += v.w;
        }
        if (j < cnt && half == 0) {
            int s = csr_src[base + j];
            float4 v = *reinterpret_cast<const float4*>(xws + (size_t)s * D + col);
            acc1.x += v.x; acc1.y += v.y; acc1.z += v.z; acc1.w += v.w;
        }
    }

    acc0.x += acc1.x + acc2.x + acc3.x;
    acc0.y += acc1.y + acc2.y + acc3.y;
    acc0.z += acc1.z + acc2.z + acc3.z;
    acc0.w += acc1.w + acc2.w + acc3.w;
    acc0.x += __shfl_down(acc0.x, 32);
    acc0.y += __shfl_down(acc0.y, 32);
    acc0.z += __shfl_down(acc0.z, 32);
    acc0.w += __shfl_down(acc0.w, 32);

    float4 r;
    r.x = fmaxf(di * (acc0.x + vs.x) + b.x, 0.f);
    r.y = fmaxf(di * (acc0.y + vs.y) + b.y, 0.f);
    r.z = fmaxf(di * (acc0.z + vs.z) + b.z, 0.f);
    r.w = fmaxf(di * (acc0.w + vs.w) + b.w, 0.f);

    if (fcw == nullptr) {
        if (half == 0)
            *reinterpret_cast<float4*>(outp + (size_t)node * D + col) = r;
    } else {
        float4 wv = *reinterpret_cast<const float4*>(fcw + col);
        float s = (half == 0) ? (r.x * wv.x + r.y * wv.y + r.z * wv.z + r.w * wv.w) : 0.f;
        #pragma unroll
        for (int off = 32; off > 0; off >>= 1) s += __shfl_down(s, off);
        if (lane == 0) fcout[node] = s + fcb[0];
    }
}

// ---------------- launch ----------------

extern "C" void kernel_launch(void* const* d_in, const int* in_sizes, int n_in,
                              void* d_out, int out_size, void* d_ws, size_t ws_size,
                              hipStream_t stream) {
    const float* x   = (const float*)d_in[0];
    const int*   ei  = (const int*)d_in[1];
    const float* W1  = (const float*)d_in[2];
    const float* b1  = (const float*)d_in[3];
    const float* W2  = (const float*)d_in[4];
    const float* b2  = (const float*)d_in[5];
    const float* W3  = (const float*)d_in[6];
    const float* b3  = (const float*)d_in[7];
    const float* Wfc = (const float*)d_in[8];
    const float* bfc = (const float*)d_in[9];
    float* outp = (float*)d_out;

    const int n = in_sizes[0] / D;        // 50000
    const int e = in_sizes[1] / 2;        // 800000
    const int* src = ei;
    const int* dst = ei + e;

    char* ws = (char*)d_ws;
    size_t off = 0;
    auto alloc = [&](size_t bytes) {
        void* p = ws + off;
        off += (bytes + 255) & ~(size_t)255;
        return p;
    };
    int*   deg     = (int*)alloc((size_t)n * 4);
    size_t zero_bytes = off;              // deg zeroed
    int*   offsets = (int*)alloc((size_t)n * 4);
    float* dinv    = (float*)alloc((size_t)n * 4);
    int*   blkSums = (int*)alloc(64 * 4);
    short* Bsw     = (short*)alloc((size_t)3 * 32768 * 2);   // pre-swizzled split W
    int*   rank    = (int*)alloc((size_t)e * 4);
    int*   csr_src = (int*)alloc((size_t)e * 4);
    float* buf0    = (float*)alloc((size_t)n * D * 4);
    float* buf1    = (float*)alloc((size_t)n * D * 4);

    int eb256 = (e + 255) / 256;
    int scan_blocks = (n + SCAN_ELEMS - 1) / SCAN_ELEMS;   // 13 (<=64)

    hipMemsetAsync(ws, 0, zero_bytes, stream);
    count_kernel <<<eb256, 256, 0, stream>>>(dst, deg, rank, e);
    scanA_kernel <<<scan_blocks, 256, 0, stream>>>(deg, blkSums, n);
    scanC_kernel <<<scan_blocks, 256, 0, stream>>>(deg, blkSums, offsets, dinv, n, scan_blocks);
    fill_kernel  <<<eb256, 256, 0, stream>>>(src, dst, offsets, rank, csr_src, e);
    wsplit_kernel<<<192, 256, 0, stream>>>(W1, W2, W3, Bsw);

    int gemm_blocks = (n + 63) / 64;      // 782
    int agg_blocks  = (n + 3) / 4;

    gemm_kernel<<<gemm_blocks, 256, 0, stream>>>(x, Bsw, dinv, buf0, n);
    agg_kernel <<<agg_blocks, 256, 0, stream>>>(buf0, csr_src, offsets, deg, dinv, b1, buf1,
                                                nullptr, nullptr, nullptr, n);
    gemm_kernel<<<gemm_blocks, 256, 0, stream>>>(buf1, Bsw + 32768, dinv, buf0, n);
    agg_kernel <<<agg_blocks, 256, 0, stream>>>(buf0, csr_src, offsets, deg, dinv, b2, buf1,
                                                nullptr, nullptr, nullptr, n);
    gemm_kernel<<<gemm_blocks, 256, 0, stream>>>(buf1, Bsw + 65536, dinv, buf0, n);
    agg_kernel <<<agg_blocks, 256, 0, stream>>>(buf0, csr_src, offsets, deg, dinv, b3, nullptr,
                                                Wfc, bfc, outp, n);
}

// Round 10
// 334.841 us; speedup vs baseline: 1.2470x; 1.0880x over previous
//
#include <hip/hip_runtime.h>

#define D 128
#define SCAN_ELEMS 4096   // elements per scan block (256 threads x 16)

typedef __attribute__((ext_vector_type(8))) short short8;
typedef __attribute__((ext_vector_type(4))) float f32x4;

// ---------------- precompute kernels ----------------
// deg[] counts REAL edges only (self-loop handled as +1 at use sites).

__global__ void count_kernel(const int* __restrict__ dst, int* __restrict__ deg,
                             int* __restrict__ rank, int e) {
    int i = blockIdx.x * blockDim.x + threadIdx.x;
    if (i < e) rank[i] = atomicAdd(&deg[dst[i]], 1);
}

__global__ __launch_bounds__(256) void scanA_kernel(const int* __restrict__ deg,
                                                    int* __restrict__ blkSums, int n) {
    __shared__ int waveSums[4];
    int t = threadIdx.x;
    int base = blockIdx.x * SCAN_ELEMS + t * 16;
    int s = 0;
    if (base + 16 <= n) {
        const int4* p = reinterpret_cast<const int4*>(deg + base);
        #pragma unroll
        for (int k = 0; k < 4; ++k) {
            int4 v = p[k];
            s += v.x + v.y + v.z + v.w;
        }
    } else {
        for (int k = 0; k < 16; ++k) {
            int i = base + k;
            if (i < n) s += deg[i];
        }
    }
    #pragma unroll
    for (int off = 32; off > 0; off >>= 1) s += __shfl_down(s, off);
    int lane = t & 63, w = t >> 6;
    if (lane == 0) waveSums[w] = s;
    __syncthreads();
    if (t == 0) blkSums[blockIdx.x] = waveSums[0] + waveSums[1] + waveSums[2] + waveSums[3];
}

// scanC: block prefix from blkSums (reduction over preceding blocks, folded in)
__global__ __launch_bounds__(256) void scanC_kernel(const int* __restrict__ deg,
                                                    const int* __restrict__ blkSums,
                                                    int* __restrict__ offsets,
                                                    float* __restrict__ dinv, int n, int nblk) {
    __shared__ int waveSums[4];
    __shared__ int blkBase;
    int t = threadIdx.x;
    int lane = t & 63, w = t >> 6;

    if (t < 64) {   // first wave: sum of blkSums[0..blockIdx.x-1]
        int s = (t < nblk && t < blockIdx.x) ? blkSums[t] : 0;
        #pragma unroll
        for (int off = 32; off > 0; off >>= 1) s += __shfl_down(s, off);
        if (t == 0) blkBase = s;
    }

    int base = blockIdx.x * SCAN_ELEMS + t * 16;
    int v[16];
    int s = 0;
    #pragma unroll
    for (int k = 0; k < 16; ++k) {
        int i = base + k;
        int d = (i < n) ? deg[i] : 0;
        v[k] = d;
        s += d;
    }
    int incl = s;
    #pragma unroll
    for (int off = 1; off < 64; off <<= 1) {
        int u = __shfl_up(incl, off);
        if (lane >= off) incl += u;
    }
    if (lane == 63) waveSums[w] = incl;
    __syncthreads();
    int waveOff = 0;
    for (int i = 0; i < 4; ++i) if (i < w) waveOff += waveSums[i];
    int off0 = blkBase + waveOff + incl - s;

    #pragma unroll
    for (int k = 0; k < 16; ++k) {
        int i = base + k;
        if (i < n) {
            offsets[i] = off0;
            dinv[i] = rsqrtf((float)(v[k] + 1));   // +1 self-loop
            off0 += v[k];
        }
    }
}

__global__ void fill_kernel(const int* __restrict__ src, const int* __restrict__ dst,
                            const int* __restrict__ offsets, const int* __restrict__ rank,
                            int* __restrict__ csr_src, int e) {
    int i = blockIdx.x * blockDim.x + threadIdx.x;
    if (i < e) {
        csr_src[offsets[dst[i]] + rank[i]] = src[i];
    }
}

// ---------------- split-bf16 helpers ----------------
__device__ inline void f2bf(float f, short& hi, short& lo) {
    union { float f; unsigned u; } a; a.f = f;
    unsigned r = a.u + 0x7fffu + ((a.u >> 16) & 1u);       // RNE to bf16
    hi = (short)(r >> 16);
    union { unsigned u; float f; } h; h.u = ((unsigned)(unsigned short)hi) << 16;
    union { float f; unsigned u; } b; b.f = f - h.f;
    unsigned r2 = b.u + 0x7fffu + ((b.u >> 16) & 1u);
    lo = (short)(r2 >> 16);
}

// fp24 encode: RNE-round fp32 to 24 bits (sign+8exp+15mant)
__device__ inline unsigned enc24(float f) {
    union { float f; unsigned u; } a; a.f = f;
    unsigned r = a.u + 0x7fu + ((a.u >> 8) & 1u);
    return r >> 8;
}

// Pre-split + swizzle the three 128x128 weight matrices into MFMA B-fragment
// order. Per layer: hi[16384 shorts] then lo[16384 shorts] (64KB total).
__global__ __launch_bounds__(256) void wsplit_kernel(const float* __restrict__ W1,
                                                     const float* __restrict__ W2,
                                                     const float* __restrict__ W3,
                                                     short* __restrict__ Bsw) {
    int tid = blockIdx.x * 256 + threadIdx.x;   // 0 .. 3*16384-1
    int layer = tid >> 14;
    int rem = tid & 16383;
    int k = rem >> 7, c = rem & 127;
    const float* Wg = (layer == 0) ? W1 : ((layer == 1) ? W2 : W3);
    float v = Wg[k * 128 + c];
    short hi, lo; f2bf(v, hi, lo);
    int ktile = k >> 5, kk = k & 31, q = kk >> 3, j = kk & 7;
    int ct = c >> 4, mm = c & 15, lane = q * 16 + mm;
    int idx = layer * 32768 + ((ktile * 8 + ct) * 64 + lane) * 8 + j;
    Bsw[idx] = hi;
    Bsw[idx + 16384] = lo;
}

// ---------------- split-bf16 MFMA GEMM -> fp24 dual-array output ----------------
// xh[r][c] = top16 of enc24(dinv[r]*(A@W)), xl[r][c] = low8.
__global__ __launch_bounds__(256) void gemm_kernel(const float* __restrict__ A,
                                                   const short* __restrict__ Bsw,
                                                   const float* __restrict__ dinv,
                                                   unsigned short* __restrict__ xh,
                                                   unsigned char* __restrict__ xl, int n) {
    __shared__ float tile[4][16][132];   // per-wave 16x128 tile (+pad)

    int t = threadIdx.x;
    int w = t >> 6;
    int lane = t & 63;
    int quad = lane >> 4;
    int m = lane & 15;

    int rowBase = blockIdx.x * 64 + w * 16;
    int arow = rowBase + m;
    bool valid = arow < n;
    const float* ap = A + (size_t)(valid ? arow : 0) * D + quad * 8;

    f32x4 acc[8];
    #pragma unroll
    for (int ct = 0; ct < 8; ++ct) acc[ct] = (f32x4){0.f, 0.f, 0.f, 0.f};

    #pragma unroll
    for (int kt = 0; kt < 4; ++kt) {
        short8 a_hi, a_lo;
        {
            float4 f0 = *reinterpret_cast<const float4*>(ap + kt * 32);
            float4 f1 = *reinterpret_cast<const float4*>(ap + kt * 32 + 4);
            float fv[8] = {f0.x, f0.y, f0.z, f0.w, f1.x, f1.y, f1.z, f1.w};
            #pragma unroll
            for (int j = 0; j < 8; ++j) {
                short h, l; f2bf(valid ? fv[j] : 0.f, h, l);
                a_hi[j] = h; a_lo[j] = l;
            }
        }
        const short* bp = Bsw + (kt * 8 * 64 + lane) * 8;
        #pragma unroll
        for (int ct = 0; ct < 8; ++ct) {
            short8 b_hi = *reinterpret_cast<const short8*>(bp + ct * 512);
            short8 b_lo = *reinterpret_cast<const short8*>(bp + 16384 + ct * 512);
            acc[ct] = __builtin_amdgcn_mfma_f32_16x16x32_bf16(a_hi, b_hi, acc[ct], 0, 0, 0);
            acc[ct] = __builtin_amdgcn_mfma_f32_16x16x32_bf16(a_hi, b_lo, acc[ct], 0, 0, 0);
            acc[ct] = __builtin_amdgcn_mfma_f32_16x16x32_bf16(a_lo, b_hi, acc[ct], 0, 0, 0);
        }
    }

    // stage scaled tile to LDS  (C/D layout: col=lane&15, row=quad*4+reg —
    // identical mapping to the round-7/8 direct store that passed)
    #pragma unroll
    for (int r = 0; r < 4; ++r) {
        int orow = rowBase + quad * 4 + r;
        float s = (orow < n) ? dinv[orow] : 0.f;
        #pragma unroll
        for (int ct = 0; ct < 8; ++ct)
            tile[w][quad * 4 + r][m + ct * 16] = acc[ct][r] * s;
    }
    __syncthreads();

    // dual store, coalesced: lane -> row (lane>>2), 32 cols at (lane&3)*32
    int r = lane >> 2;
    int c0 = (lane & 3) << 5;
    int gr = rowBase + r;
    if (gr < n) {
        unsigned hu[16], lu[8];
        #pragma unroll
        for (int g = 0; g < 8; ++g) {
            float4 f = *reinterpret_cast<const float4*>(&tile[w][r][c0 + g * 4]);
            unsigned e0 = enc24(f.x), e1 = enc24(f.y), e2 = enc24(f.z), e3 = enc24(f.w);
            hu[g * 2]     = (e0 >> 8) | ((e1 >> 8) << 16);
            hu[g * 2 + 1] = (e2 >> 8) | ((e3 >> 8) << 16);
            lu[g] = (e0 & 0xffu) | ((e1 & 0xffu) << 8) | ((e2 & 0xffu) << 16) | ((e3 & 0xffu) << 24);
        }
        uint4* hp = reinterpret_cast<uint4*>(xh + (size_t)gr * 128 + c0);   // 64B-aligned
        uint4* lp = reinterpret_cast<uint4*>(xl + (size_t)gr * 128 + c0);   // 32B-aligned
        hp[0] = *reinterpret_cast<uint4*>(&hu[0]);
        hp[1] = *reinterpret_cast<uint4*>(&hu[4]);
        hp[2] = *reinterpret_cast<uint4*>(&hu[8]);
        hp[3] = *reinterpret_cast<uint4*>(&hu[12]);
        lp[0] = *reinterpret_cast<uint4*>(&lu[0]);
        lp[1] = *reinterpret_cast<uint4*>(&lu[4]);
    }
}

// ---------------- aggregation (+ optional fused fc head) ----------------
// xws rows fp24 dual-array, pre-scaled by dinv[row]:
//   h[d] = relu( dinv[d] * (sum_{e:s->d} xws[s] + xws[d]) + b )
// Structure is round-8's passing half-wave agg verbatim; only the row load
// changed (uint2 + uint -> 4 decoded floats).

__device__ inline void g24(const unsigned short* __restrict__ xh,
                           const unsigned char* __restrict__ xl,
                           int row, int c, float4& a) {
    uint2 h2 = *reinterpret_cast<const uint2*>(xh + (size_t)row * 128 + c);
    unsigned lb = *reinterpret_cast<const unsigned*>(xl + (size_t)row * 128 + c);
    union { unsigned u; float f; } v0, v1, v2, v3;
    v0.u = ((h2.x & 0xffffu) << 16) | ((lb & 0xffu) << 8);
    v1.u = (h2.x & 0xffff0000u)     | (((lb >> 8) & 0xffu) << 8);
    v2.u = ((h2.y & 0xffffu) << 16) | (((lb >> 16) & 0xffu) << 8);
    v3.u = (h2.y & 0xffff0000u)     | ((lb >> 24) << 8);
    a.x += v0.f; a.y += v1.f; a.z += v2.f; a.w += v3.f;
}

__global__ __launch_bounds__(256) void agg_kernel(const unsigned short* __restrict__ xh,
                                                  const unsigned char* __restrict__ xl,
                                                  const int* __restrict__ csr_src,
                                                  const int* __restrict__ offsets,
                                                  const int* __restrict__ deg,
                                                  const float* __restrict__ dinv,
                                                  const float* __restrict__ bias,
                                                  float* __restrict__ outp,
                                                  const float* __restrict__ fcw,
                                                  const float* __restrict__ fcb,
                                                  float* __restrict__ fcout,
                                                  int n) {
    int wave = (blockIdx.x * blockDim.x + threadIdx.x) >> 6;
    int lane = threadIdx.x & 63;
    if (wave >= n) return;
    int node = wave;
    int half = lane >> 5;
    int l32  = lane & 31;
    int col  = l32 << 2;

    int base = offsets[node];
    int cnt  = deg[node];

    float di = dinv[node];
    float4 vs = make_float4(0.f, 0.f, 0.f, 0.f);
    g24(xh, xl, node, col, vs);
    float4 b = *reinterpret_cast<const float4*>(bias + col);

    float4 acc0 = make_float4(0.f, 0.f, 0.f, 0.f);
    float4 acc1 = make_float4(0.f, 0.f, 0.f, 0.f);
    float4 acc2 = make_float4(0.f, 0.f, 0.f, 0.f);
    float4 acc3 = make_float4(0.f, 0.f, 0.f, 0.f);

    if (cnt <= 64) {
        int idx = (lane < cnt) ? csr_src[base + lane] : 0;
        int j = 0;
        for (; j + 8 <= cnt; j += 8) {
            int s0 = __shfl(idx, j     + half);
            int s1 = __shfl(idx, j + 2 + half);
            int s2 = __shfl(idx, j + 4 + half);
            int s3 = __shfl(idx, j + 6 + half);
            g24(xh, xl, s0, col, acc0);
            g24(xh, xl, s1, col, acc1);
            g24(xh, xl, s2, col, acc2);
            g24(xh, xl, s3, col, acc3);
        }
        for (; j + 2 <= cnt; j += 2) {
            int s0 = __shfl(idx, j + half);
            g24(xh, xl, s0, col, acc0);
        }
        if (j < cnt) {
            int s0 = __shfl(idx, j);
            if (half == 0) g24(xh, xl, s0, col, acc1);
        }
    } else {
        int j = 0;
        for (; j + 2 <= cnt; j += 2) {
            int s = csr_src[base + j + half];
            g24(xh, xl, s, col, acc0);
        }
        if (j < cnt && half == 0) {
            int s = csr_src[base + j];
            g24(xh, xl, s, col, acc1);
        }
    }

    acc0.x += acc1.x + acc2.x + acc3.x;
    acc0.y += acc1.y + acc2.y + acc3.y;
    acc0.z += acc1.z + acc2.z + acc3.z;
    acc0.w += acc1.w + acc2.w + acc3.w;
    acc0.x += __shfl_down(acc0.x, 32);
    acc0.y += __shfl_down(acc0.y, 32);
    acc0.z += __shfl_down(acc0.z, 32);
    acc0.w += __shfl_down(acc0.w, 32);

    float4 r;
    r.x = fmaxf(di * (acc0.x + vs.x) + b.x, 0.f);
    r.y = fmaxf(di * (acc0.y + vs.y) + b.y, 0.f);
    r.z = fmaxf(di * (acc0.z + vs.z) + b.z, 0.f);
    r.w = fmaxf(di * (acc0.w + vs.w) + b.w, 0.f);

    if (fcw == nullptr) {
        if (half == 0)
            *reinterpret_cast<float4*>(outp + (size_t)node * D + col) = r;
    } else {
        float4 wv = *reinterpret_cast<const float4*>(fcw + col);
        float s = (half == 0) ? (r.x * wv.x + r.y * wv.y + r.z * wv.z + r.w * wv.w) : 0.f;
        #pragma unroll
        for (int off = 32; off > 0; off >>= 1) s += __shfl_down(s, off);
        if (lane == 0) fcout[node] = s + fcb[0];
    }
}

// ---------------- launch ----------------

extern "C" void kernel_launch(void* const* d_in, const int* in_sizes, int n_in,
                              void* d_out, int out_size, void* d_ws, size_t ws_size,
                              hipStream_t stream) {
    const float* x   = (const float*)d_in[0];
    const int*   ei  = (const int*)d_in[1];
    const float* W1  = (const float*)d_in[2];
    const float* b1  = (const float*)d_in[3];
    const float* W2  = (const float*)d_in[4];
    const float* b2  = (const float*)d_in[5];
    const float* W3  = (const float*)d_in[6];
    const float* b3  = (const float*)d_in[7];
    const float* Wfc = (const float*)d_in[8];
    const float* bfc = (const float*)d_in[9];
    float* outp = (float*)d_out;

    const int n = in_sizes[0] / D;        // 50000
    const int e = in_sizes[1] / 2;        // 800000
    const int* src = ei;
    const int* dst = ei + e;

    char* ws = (char*)d_ws;
    size_t off = 0;
    auto alloc = [&](size_t bytes) {
        void* p = ws + off;
        off += (bytes + 255) & ~(size_t)255;
        return p;
    };
    int*            deg     = (int*)alloc((size_t)n * 4);
    size_t          zero_bytes = off;     // deg zeroed
    int*            offsets = (int*)alloc((size_t)n * 4);
    float*          dinv    = (float*)alloc((size_t)n * 4);
    int*            blkSums = (int*)alloc(64 * 4);
    short*          Bsw     = (short*)alloc((size_t)3 * 32768 * 2);
    int*            rank    = (int*)alloc((size_t)e * 4);
    int*            csr_src = (int*)alloc((size_t)e * 4);
    unsigned short* xhbuf   = (unsigned short*)alloc((size_t)n * 128 * 2);  // fp24 hi16
    unsigned char*  xlbuf   = (unsigned char*)alloc((size_t)n * 128);       // fp24 lo8
    float*          buf1    = (float*)alloc((size_t)n * D * 4);             // fp32 h

    int eb256 = (e + 255) / 256;
    int scan_blocks = (n + SCAN_ELEMS - 1) / SCAN_ELEMS;   // 13 (<=64)

    hipMemsetAsync(ws, 0, zero_bytes, stream);
    count_kernel <<<eb256, 256, 0, stream>>>(dst, deg, rank, e);
    scanA_kernel <<<scan_blocks, 256, 0, stream>>>(deg, blkSums, n);
    scanC_kernel <<<scan_blocks, 256, 0, stream>>>(deg, blkSums, offsets, dinv, n, scan_blocks);
    fill_kernel  <<<eb256, 256, 0, stream>>>(src, dst, offsets, rank, csr_src, e);
    wsplit_kernel<<<192, 256, 0, stream>>>(W1, W2, W3, Bsw);

    int gemm_blocks = (n + 63) / 64;      // 782
    int agg_blocks  = (n + 3) / 4;

    gemm_kernel<<<gemm_blocks, 256, 0, stream>>>(x, Bsw, dinv, xhbuf, xlbuf, n);
    agg_kernel <<<agg_blocks, 256, 0, stream>>>(xhbuf, xlbuf, csr_src, offsets, deg, dinv, b1, buf1,
                                                nullptr, nullptr, nullptr, n);
    gemm_kernel<<<gemm_blocks, 256, 0, stream>>>(buf1, Bsw + 32768, dinv, xhbuf, xlbuf, n);
    agg_kernel <<<agg_blocks, 256, 0, stream>>>(xhbuf, xlbuf, csr_src, offsets, deg, dinv, b2, buf1,
                                                nullptr, nullptr, nullptr, n);
    gemm_kernel<<<gemm_blocks, 256, 0, stream>>>(buf1, Bsw + 65536, dinv, xhbuf, xlbuf, n);
    agg_kernel <<<agg_blocks, 256, 0, stream>>>(xhbuf, xlbuf, csr_src, offsets, deg, dinv, b3, nullptr,
                                                Wfc, bfc, outp, n);
}